// Round 1
// 454.366 us; speedup vs baseline: 1.0156x; 1.0156x over previous
//
#include <hip/hip_runtime.h>

// Spherical harmonics, L=20 (400 cols), B=250000, fp32 out.
// R3: m-partitioned chains — no redundant compute.
// 64 points/block, 256 threads (4 waves). The Legendre recurrence for
// fixed m is an independent chain over l, so each wave owns a balanced
// subset of m's (SUBOF table) and computes ONLY its chains (the P[m,m]
// double-factorial sweep and cos/sin(m*phi) angle-addition sweep are
// ~19 FMAs each, run by all waves). This removes the 4x redundant
// recurrence and the Pa/Pb/Pc[20] register arrays of R2.
// LDS staging + coalesced flush identical to R2 (proven):
// two column chunks ([0,196) and [196,400)) share one 64x205 LDS tile;
// cooperative flush emits contiguous coalesced runs; each block fully
// covers a contiguous 100KB global region -> ~1.0x write traffic.

#define L_MAX 20
#define NCOL 400
#define PTS 64          // points per block
#define TPB 256         // 4 waves
#define LSTR 205        // LDS row stride (floats); 205 mod 32 = 13, coprime -> conflict-free
#define SPLIT_L 14      // 14*14 = 196
#define C0A 0
#define CA 196
#define C0B 196
#define CB 204

// ---- compile-time double sqrt via Newton ----
constexpr double csqrt(double x) {
    double g = (x > 1.0) ? x : 1.0;
    for (int i = 0; i < 200; ++i) g = 0.5 * (g + x / g);
    return g;
}

struct CoefTbl { float c[NCOL]; };

constexpr CoefTbl make_tbl() {
    CoefTbl t{};
    const double PI  = 3.14159265358979323846;
    const double SQ2 = csqrt(2.0);
    for (int l = 0; l < L_MAX; ++l) {
        for (int m = 0; m <= l; ++m) {
            double r = 1.0;
            for (int k = l - m + 1; k <= l + m; ++k) r /= (double)k;
            double K = csqrt((2.0 * l + 1.0) / (4.0 * PI) * r);
            int base = l * l + l;
            if (m == 0) {
                t.c[base] = (float)K;
            } else {
                t.c[base + m] = (float)(SQ2 * K);
                t.c[base - m] = (float)(SQ2 * K);
            }
        }
    }
    return t;
}

static constexpr CoefTbl TBL = make_tbl();

// m -> wave assignment, balanced across both passes.
// Pass A emit sums (weight 14-m, m<14): 27/26/26/26
// Pass B emit sums (6 for m<14, 20-m else): 27/27/26/25
__device__ constexpr int SUBOF[L_MAX] =
    {0,1,2,3, 3,2,1,0, 0,1,2,3, 3,2, 1,0,0,1, 2,3};

// One column-chunk pass: run every owned m-chain, emit cols with
// L0 <= l < L1 into the LDS row at (global col - C0).
template<int L0, int L1, int C0>
__device__ __forceinline__ void sh_pass(int sub, float x, float sx,
                                        float c1, float s1,
                                        float* __restrict__ myrow) {
    constexpr int LTOP = L1 - 1;     // last l this pass ever emits
    float pm = 1.0f;                 // P[m,m] sweep
    float cv = 1.0f, sv = 0.0f;      // cos(m*phi), sin(m*phi) sweep

    auto emit = [&](int l, int m, float p) {
        if (l < L0) return;          // folds at compile time (unrolled)
        const int g = l * l + l;
        const int b = g - C0;
        if (m == 0) {
            myrow[b] = TBL.c[g] * p;
        } else {
            const float t = TBL.c[g + m] * p;
            myrow[b + m] = t * cv;
            myrow[b - m] = t * sv;
        }
    };

#pragma unroll
    for (int m = 0; m <= LTOP; ++m) {
        if (SUBOF[m] == sub) {       // wave-uniform branch
            float p2 = pm;           // P[m,m]
            emit(m, m, p2);
            if (m + 1 <= LTOP) {
                float p1 = float(2 * m + 1) * x * p2;   // P[m+1,m]
                emit(m + 1, m, p1);
#pragma unroll
                for (int l = m + 2; l <= LTOP; ++l) {
                    float p0 = (float(2 * l - 1) * x * p1 -
                                float(l + m - 1) * p2) *
                               (1.0f / float(l - m));
                    emit(l, m, p0);
                    p2 = p1; p1 = p0;
                }
            }
        }
        if (m < LTOP) {              // advance sweeps (all waves)
            pm = -float(2 * m + 1) * sx * pm;
            float cn = cv * c1 - sv * s1;
            sv = sv * c1 + cv * s1;
            cv = cn;
        }
    }
}

__global__ __launch_bounds__(TPB, 3) void sh_kernel(const float2* __restrict__ lonlat,
                                                    float* __restrict__ out, int B) {
    __shared__ float tile[PTS * LSTR];

    const int tid  = threadIdx.x;
    const int lane = tid & 63;     // point within block
    const int sub  = tid >> 6;     // wave id (uniform per wave)
    const int blockBase = blockIdx.x * PTS;
    const int p  = blockBase + lane;
    const int pr = p < B ? p : B - 1;

    float2 ll = lonlat[pr];
    const float D2R = 0.017453292519943295f;
    float phi   = (ll.x + 180.0f) * D2R;
    float theta = (ll.y + 90.0f) * D2R;

    float x, sx, s1, c1;
    sincosf(theta, &sx, &x);   // sx = sin(theta), x = cos(theta)
    sincosf(phi, &s1, &c1);

    float* myrow = tile + lane * LSTR;

    // ---- chunk A: l = 0..13 -> global cols [0,196) ----
    sh_pass<0, SPLIT_L, C0A>(sub, x, sx, c1, s1, myrow);

    __syncthreads();
    for (int i = tid; i < PTS * CA; i += TPB) {
        int pp = i / CA;                   // constant divisor -> magic mul
        int cc = i - pp * CA;
        int gp = blockBase + pp;
        if (gp < B) out[(size_t)gp * NCOL + C0A + cc] = tile[pp * LSTR + cc];
    }
    __syncthreads();

    // ---- chunk B: l = 14..19 -> global cols [196,400), stored at col-196 ----
    sh_pass<SPLIT_L, L_MAX, C0B>(sub, x, sx, c1, s1, myrow);

    __syncthreads();
    for (int i = tid; i < PTS * CB; i += TPB) {
        int pp = i / CB;
        int cc = i - pp * CB;
        int gp = blockBase + pp;
        if (gp < B) out[(size_t)gp * NCOL + C0B + cc] = tile[pp * LSTR + cc];
    }
}

extern "C" void kernel_launch(void* const* d_in, const int* in_sizes, int n_in,
                              void* d_out, int out_size, void* d_ws, size_t ws_size,
                              hipStream_t stream) {
    (void)n_in; (void)d_ws; (void)ws_size; (void)out_size;
    const float2* lonlat = (const float2*)d_in[0];
    float* out = (float*)d_out;
    int B = in_sizes[0] / 2;

    const int blocks = (B + PTS - 1) / PTS;
    sh_kernel<<<blocks, TPB, 0, stream>>>(lonlat, out, B);
}

// Round 2
// 445.969 us; speedup vs baseline: 1.0347x; 1.0188x over previous
//
#include <hip/hip_runtime.h>

// Spherical harmonics, L=20 (400 cols), B=250000, fp32 out.
// R4: float4 flush. R3's m-partitioned compute kept (compute ~13us, not
// the bottleneck). The flush is rewritten to 16B/lane: 4 consecutive LDS
// floats (2x ds_read2_b32, 4B-align legal -> LSTR stays odd=conflict-free)
// + one global_store_dwordx4 (row base 1600B, cc%4==0 -> 16B aligned).
// ~4x fewer flush instructions, 1KB/wave stores. Block-uniform tail guard;
// 32-bit offsets off a hoisted per-block output base.

#define L_MAX 20
#define NCOL 400
#define PTS 64          // points per block
#define TPB 256         // 4 waves
#define LSTR 205        // LDS row stride (floats); 205 mod 32 = 13, coprime -> conflict-free emits
#define SPLIT_L 14      // 14*14 = 196
#define C0A 0
#define CA 196
#define C0B 196
#define CB 204

// ---- compile-time double sqrt via Newton ----
constexpr double csqrt(double x) {
    double g = (x > 1.0) ? x : 1.0;
    for (int i = 0; i < 200; ++i) g = 0.5 * (g + x / g);
    return g;
}

struct CoefTbl { float c[NCOL]; };

constexpr CoefTbl make_tbl() {
    CoefTbl t{};
    const double PI  = 3.14159265358979323846;
    const double SQ2 = csqrt(2.0);
    for (int l = 0; l < L_MAX; ++l) {
        for (int m = 0; m <= l; ++m) {
            double r = 1.0;
            for (int k = l - m + 1; k <= l + m; ++k) r /= (double)k;
            double K = csqrt((2.0 * l + 1.0) / (4.0 * PI) * r);
            int base = l * l + l;
            if (m == 0) {
                t.c[base] = (float)K;
            } else {
                t.c[base + m] = (float)(SQ2 * K);
                t.c[base - m] = (float)(SQ2 * K);
            }
        }
    }
    return t;
}

static constexpr CoefTbl TBL = make_tbl();

// m -> wave assignment, balanced across both passes.
__device__ constexpr int SUBOF[L_MAX] =
    {0,1,2,3, 3,2,1,0, 0,1,2,3, 3,2, 1,0,0,1, 2,3};

// One column-chunk pass: run every owned m-chain, emit cols with
// L0 <= l < L1 into the LDS row at (global col - C0).
template<int L0, int L1, int C0>
__device__ __forceinline__ void sh_pass(int sub, float x, float sx,
                                        float c1, float s1,
                                        float* __restrict__ myrow) {
    constexpr int LTOP = L1 - 1;     // last l this pass ever emits
    float pm = 1.0f;                 // P[m,m] sweep
    float cv = 1.0f, sv = 0.0f;      // cos(m*phi), sin(m*phi) sweep

    auto emit = [&](int l, int m, float p) {
        if (l < L0) return;          // folds at compile time (unrolled)
        const int g = l * l + l;
        const int b = g - C0;
        if (m == 0) {
            myrow[b] = TBL.c[g] * p;
        } else {
            const float t = TBL.c[g + m] * p;
            myrow[b + m] = t * cv;
            myrow[b - m] = t * sv;
        }
    };

#pragma unroll
    for (int m = 0; m <= LTOP; ++m) {
        if (SUBOF[m] == sub) {       // wave-uniform branch
            float p2 = pm;           // P[m,m]
            emit(m, m, p2);
            if (m + 1 <= LTOP) {
                float p1 = float(2 * m + 1) * x * p2;   // P[m+1,m]
                emit(m + 1, m, p1);
#pragma unroll
                for (int l = m + 2; l <= LTOP; ++l) {
                    float p0 = (float(2 * l - 1) * x * p1 -
                                float(l + m - 1) * p2) *
                               (1.0f / float(l - m));
                    emit(l, m, p0);
                    p2 = p1; p1 = p0;
                }
            }
        }
        if (m < LTOP) {              // advance sweeps (all waves)
            pm = -float(2 * m + 1) * sx * pm;
            float cn = cv * c1 - sv * s1;
            sv = sv * c1 + cv * s1;
            cv = cn;
        }
    }
}

// Flush CW columns (multiple of 4) starting at global col C0.
// 16B per thread-iteration: 4 LDS floats -> one dwordx4 store.
template<int C0, int CW>
__device__ __forceinline__ void flush(const float* __restrict__ tile,
                                      float* __restrict__ outBase,
                                      int tid, int rem) {
    constexpr int G = CW / 4;        // float4 groups per row
    constexpr int N = PTS * G;
    if (rem >= PTS) {
#pragma unroll 4
        for (int i = tid; i < N; i += TPB) {
            int pp = i / G;                  // constant divisor -> magic mul
            int cc = (i - pp * G) * 4;
            const float* s = tile + pp * LSTR + cc;
            float4 v = make_float4(s[0], s[1], s[2], s[3]);
            *reinterpret_cast<float4*>(outBase + pp * NCOL + C0 + cc) = v;
        }
    } else {
        for (int i = tid; i < N; i += TPB) {
            int pp = i / G;
            int cc = (i - pp * G) * 4;
            if (pp < rem) {
                const float* s = tile + pp * LSTR + cc;
                float4 v = make_float4(s[0], s[1], s[2], s[3]);
                *reinterpret_cast<float4*>(outBase + pp * NCOL + C0 + cc) = v;
            }
        }
    }
}

__global__ __launch_bounds__(TPB, 3) void sh_kernel(const float2* __restrict__ lonlat,
                                                    float* __restrict__ out, int B) {
    __shared__ float tile[PTS * LSTR];

    const int tid  = threadIdx.x;
    const int lane = tid & 63;     // point within block
    const int sub  = tid >> 6;     // wave id (uniform per wave)
    const int blockBase = blockIdx.x * PTS;
    const int rem = B - blockBase; // valid points in this block
    const int p  = blockBase + lane;
    const int pr = p < B ? p : B - 1;

    float2 ll = lonlat[pr];
    const float D2R = 0.017453292519943295f;
    float phi   = (ll.x + 180.0f) * D2R;
    float theta = (ll.y + 90.0f) * D2R;

    float x, sx, s1, c1;
    sincosf(theta, &sx, &x);   // sx = sin(theta), x = cos(theta)
    sincosf(phi, &s1, &c1);

    float* myrow = tile + lane * LSTR;
    float* outBase = out + (size_t)blockBase * NCOL;

    // ---- chunk A: l = 0..13 -> global cols [0,196) ----
    sh_pass<0, SPLIT_L, C0A>(sub, x, sx, c1, s1, myrow);

    __syncthreads();
    flush<C0A, CA>(tile, outBase, tid, rem);
    __syncthreads();

    // ---- chunk B: l = 14..19 -> global cols [196,400), stored at col-196 ----
    sh_pass<SPLIT_L, L_MAX, C0B>(sub, x, sx, c1, s1, myrow);

    __syncthreads();
    flush<C0B, CB>(tile, outBase, tid, rem);
}

extern "C" void kernel_launch(void* const* d_in, const int* in_sizes, int n_in,
                              void* d_out, int out_size, void* d_ws, size_t ws_size,
                              hipStream_t stream) {
    (void)n_in; (void)d_ws; (void)ws_size; (void)out_size;
    const float2* lonlat = (const float2*)d_in[0];
    float* out = (float*)d_out;
    int B = in_sizes[0] / 2;

    const int blocks = (B + PTS - 1) / PTS;
    sh_kernel<<<blocks, TPB, 0, stream>>>(lonlat, out, B);
}